// Round 12
// baseline (164.632 us; speedup 1.0000x reference)
//
#include <hip/hip_runtime.h>
#include <math.h>

#define BB 256
#define SS 4096
#define FF 8
#define HH 32
#define TT 256              // timesteps per LDS tile
#define NT (SS/TT)          // 16 tiles
#define NTHREADS 1024
#define NG 16               // chunks per tile (one wave per chunk)
#define CLR 16              // rows per chunk
#define HROW 20             // h1h row stride in dwords (80B: 16B-aligned, 2-way max)

#define L2E  1.4426950408889634f
#define LN2f 0.6931471805599453f

typedef _Float16 f16x8 __attribute__((ext_vector_type(8)));
typedef float    f32x4 __attribute__((ext_vector_type(4)));
typedef __fp16   pk16  __attribute__((ext_vector_type(2)));   // cvt_pkrtz return type

__device__ __forceinline__ float fexp2(float x){
#if __has_builtin(__builtin_amdgcn_exp2f)
    return __builtin_amdgcn_exp2f(x);
#else
    return exp2f(x);
#endif
}
__device__ __forceinline__ float flog2(float x){
#if __has_builtin(__builtin_amdgcn_logf)
    return __builtin_amdgcn_logf(x);
#else
    return log2f(x);
#endif
}
__device__ __forceinline__ float frcp(float x){
#if __has_builtin(__builtin_amdgcn_rcpf)
    return __builtin_amdgcn_rcpf(x);
#else
    return 1.0f/x;
#endif
}

// softplus(z) = max(z,0) + ln2*log2(1 + 2^(-|z|*log2e))
__device__ __forceinline__ float softplus_n(float z){
    const float t = fexp2(-fabsf(z) * L2E);
    return fmaxf(z, 0.f) + LN2f * flog2(1.f + t);
}
// sigmoid(z) = 1/(1 + 2^(-z*log2e))
__device__ __forceinline__ float sigmoid_n(float z){
    return frcp(1.f + fexp2(-z * L2E));
}

__global__ __attribute__((amdgpu_flat_work_group_size(NTHREADS, NTHREADS),
                          amdgpu_waves_per_eu(4, 4)))
void forecast_fused(const float* __restrict__ x,
                    const float* __restrict__ Wemb, const float* __restrict__ bemb,
                    const float* __restrict__ Wd,   const float* __restrict__ bd,
                    const float* __restrict__ Alog,
                    const float* __restrict__ Wg,   const float* __restrict__ bg,
                    const float* __restrict__ gmma, const float* __restrict__ beta,
                    const float* __restrict__ W1,   const float* __restrict__ b1,
                    const float* __restrict__ W2,   const float* __restrict__ b2,
                    float* __restrict__ out)
{
    __shared__ __align__(16) unsigned int xs16[TT][4];    // x tile f16 (wave-private)  4 KB
    __shared__ __align__(16) unsigned int h1h[TT][HROW];  // h1 f16 (wave-private)     20 KB
    __shared__ float wdpS[FF][HH];         // Wemb@Wd1 composed
    __shared__ float wgpS[FF][HH];         // Wemb@Wg1 composed
    __shared__ float bdpS[HH], bgpS[HH];   // composed biases
    __shared__ float2 cfS[2][NG][HH];      // block-1 chunk totals (A,X), parity dbuf
    __shared__ float2 cf2S[2][NG][HH];     // block-2 chunk totals (A,X), parity dbuf
    __shared__ float s1s[2][HH];           // block-1 running state (parity dbuf)
    __shared__ float hlast[HH];            // exact f32 h1 of last row (head)

    const int tid  = threadIdx.x;
    const int lane = tid & 63;
    const int g    = tid >> 6;             // chunk index == wave index
    const int c0   = lane & 15;            // MFMA D col (channel, low half)
    const int grp  = lane >> 4;            // lane group 0..3 -> rows grp*4..+3
    const int r0   = grp * 4;
    const int cb   = g * CLR;              // chunk row base (tile-local)
    const int b    = blockIdx.x;
    const int lm16 = (lane - 16) & 63, lm32 = (lane - 32) & 63;
    // wave-local x staging: lane covers row cb+(lane>>2), dword pair (lane&3)
    const int srow = cb + (lane >> 2);
    const int sdc  = lane & 3;

    // ---- one-time: compose block-1 weights through the embedding ----
    if (tid < FF * HH) {
        const int f = tid >> 5, cc = tid & 31;
        float accd = 0.f, accg = 0.f;
#pragma unroll
        for (int k = 0; k < HH; ++k) {
            const float w = Wemb[f * HH + k];
            accd += w * Wd[k * HH + cc];
            accg += w * Wg[k * HH + cc];
        }
        wdpS[f][cc] = accd;
        wgpS[f][cc] = accg;
    }
    if (tid < HH) {
        float ad = bd[tid], ag = bg[tid];
#pragma unroll
        for (int k = 0; k < HH; ++k) {
            ad += bemb[k] * Wd[k * HH + tid];
            ag += bemb[k] * Wg[k * HH + tid];
        }
        bdpS[tid] = ad; bgpS[tid] = ag;
        s1s[0][tid] = 0.f;
    }
    __syncthreads();

    // ---- B-fragments (k = (lane>>4)*8 + j; same chosen k-order for A and B)
    //      and per-channel constants for this lane's two columns ----
    f16x8 bh0[2], bzd[2], bzg[2], bwd2[2];
    float bec[2], bd1p[2], bg1p[2], bd2c[2], nA1[2], nA2[2];
#pragma unroll
    for (int q = 0; q < 2; ++q) {
        const int cq = c0 + 16 * q;
#pragma unroll
        for (int j = 0; j < 8; ++j) {
            // D1 operands: K=8 padded to 32 -> only k-block 0 (lanes<16) is real
            bh0[q][j] = (lane < 16) ? (_Float16)Wemb[j * HH + cq] : (_Float16)0.f;
            bzd[q][j] = (lane < 16) ? (_Float16)wdpS[j][cq]       : (_Float16)0.f;
            bzg[q][j] = (lane < 16) ? (_Float16)wgpS[j][cq]       : (_Float16)0.f;
            // D2 operand: full K=32
            bwd2[q][j] = (_Float16)Wd[HH * HH + (grp * 8 + j) * HH + cq];
        }
        bec[q]  = bemb[cq];
        bd1p[q] = bdpS[cq]; bg1p[q] = bgpS[cq];
        bd2c[q] = bd[HH + cq];
        nA1[q] = -expf(Alog[cq]) * L2E;
        nA2[q] = -expf(Alog[HH + cq]) * L2E;
    }

    float s2v = 0.f;                       // block-2 running carry (wave0 lanes<32)

    // ---- prologue: each wave stages its own rows of tile 0 ----
    {
        const float2 xv = *reinterpret_cast<const float2*>(
            x + ((size_t)b * SS + srow) * FF + sdc * 2);
        const pk16 pk = __builtin_amdgcn_cvt_pkrtz(xv.x, xv.y);
        xs16[srow][sdc] = __builtin_bit_cast(unsigned int, pk);
        // intra-wave DS FIFO: D1's read below is ordered after this write
    }

    for (int it = 0; it < NT; ++it) {
        const int p = it & 1;

        // ---- prefetch next x tile rows into registers (wave-local) ----
        float2 xnext = make_float2(0.f, 0.f);
        if (it + 1 < NT)
            xnext = *reinterpret_cast<const float2*>(
                x + ((size_t)b * SS + (it + 1) * TT + srow) * FF + sdc * 2);

        // ---- D1: h0/zd1/zg1 via MFMA (A = own x rows, K=8 padded) ----
        uint4 aw = make_uint4(0u, 0u, 0u, 0u);
        if (lane < 16) aw = *reinterpret_cast<const uint4*>(&xs16[cb + c0][0]);
        const f16x8 a1 = __builtin_bit_cast(f16x8, aw);
        f32x4 vh0[2], vzd[2], vzg[2];
#pragma unroll
        for (int q = 0; q < 2; ++q) {
            f32x4 cin;
            cin[0] = cin[1] = cin[2] = cin[3] = bec[q];
            vh0[q] = __builtin_amdgcn_mfma_f32_16x16x32_f16(a1, bh0[q], cin, 0, 0, 0);
            cin[0] = cin[1] = cin[2] = cin[3] = bd1p[q];
            vzd[q] = __builtin_amdgcn_mfma_f32_16x16x32_f16(a1, bzd[q], cin, 0, 0, 0);
            cin[0] = cin[1] = cin[2] = cin[3] = bg1p[q];
            vzg[q] = __builtin_amdgcn_mfma_f32_16x16x32_f16(a1, bzg[q], cin, 0, 0, 0);
        }

        // ---- pointwise + group-local (4-row) scan, in registers ----
        float pA[2][4], pl[2][4], gt[2][4], h1v[2][4];
#pragma unroll
        for (int q = 0; q < 2; ++q) {
            float sp = 1.f, sl = 0.f;
#pragma unroll
            for (int j = 0; j < 4; ++j) {
                const float delta = softplus_n(vzd[q][j]);
                const float ab    = fexp2(delta * nA1[q]);
                sl = ab * sl + delta * vh0[q][j];
                sp *= ab;
                pA[q][j] = sp; pl[q][j] = sl;
                gt[q][j] = sigmoid_n(vzg[q][j]);
            }
        }
        // Kogge-Stone inclusive scan of (A,X) over the 4 lane-groups
        float P[2], S[2];
        P[0] = pA[0][3]; S[0] = pl[0][3];
        P[1] = pA[1][3]; S[1] = pl[1][3];
#pragma unroll
        for (int q = 0; q < 2; ++q) {
            float Pm = __shfl(P[q], lm16), Sm = __shfl(S[q], lm16);
            if (grp >= 1) { S[q] = P[q] * Sm + S[q]; P[q] = P[q] * Pm; }
            float Pm2 = __shfl(P[q], lm32), Sm2 = __shfl(S[q], lm32);
            if (grp >= 2) { S[q] = P[q] * Sm2 + S[q]; P[q] = P[q] * Pm2; }
        }
        if (grp == 3) {                       // chunk totals
            cfS[p][g][c0]      = make_float2(P[0], S[0]);
            cfS[p][g][c0 + 16] = make_float2(P[1], S[1]);
        }
        __syncthreads();                      // THE barrier (1 per tile)

        // ---- COMB1: per-lane carry chain for channel (lane&31) ----
        const int chc = lane & 31;
        float cy = s1s[p][chc];
#pragma unroll
        for (int ch = 0; ch < NG; ++ch) {
            const float2 ax = cfS[p][ch][chc];
            const float t = ax.x * cy + ax.y;
            cy = (ch < g) ? t : cy;
        }
        if (g == NG - 1 && lane < 32) {
            const float2 aL = cfS[p][NG - 1][chc];
            s1s[p ^ 1][chc] = aL.x * cy + aL.y;
        }
        const float cyq0 = __shfl(cy, c0);
        const float cyq1 = __shfl(cy, c0 + 16);
        float gin[2];
#pragma unroll
        for (int q = 0; q < 2; ++q) {
            float Pe = __shfl(P[q], lm16), Se = __shfl(S[q], lm16);
            if (grp == 0) { Pe = 1.f; Se = 0.f; }
            gin[q] = Se + Pe * (q ? cyq1 : cyq0);
        }

        // ---- C1: fixup + residual gate; pack h1 rows to f16 LDS (own rows) ----
#pragma unroll
        for (int q = 0; q < 2; ++q)
#pragma unroll
            for (int j = 0; j < 4; ++j) {
                const float st = pl[q][j] + pA[q][j] * gin[q];
                h1v[q][j] = vh0[q][j] + st * gt[q][j];
            }
#pragma unroll
        for (int j = 0; j < 4; ++j) {
            const float p0 = __shfl_xor(h1v[0][j], 1);
            const float p1 = __shfl_xor(h1v[1][j], 1);
            unsigned int w;
            if (lane & 1) {
                const pk16 pk = __builtin_amdgcn_cvt_pkrtz(p1, h1v[1][j]);
                w = __builtin_bit_cast(unsigned int, pk);
            } else {
                const pk16 pk = __builtin_amdgcn_cvt_pkrtz(h1v[0][j], p0);
                w = __builtin_bit_cast(unsigned int, pk);
            }
            h1h[cb + r0 + j][(c0 >> 1) + ((lane & 1) ? 8 : 0)] = w;
        }
        if (it == NT - 1 && g == NG - 1 && grp == 3) {
            hlast[c0]      = h1v[0][3];
            hlast[c0 + 16] = h1v[1][3];
        }

        // ---- D2: zd2 via MFMA (A = own h1 rows, K=32); scan in regs ----
        const uint4 aw2 = *reinterpret_cast<const uint4*>(&h1h[cb + c0][grp * 4]);
        const f16x8 a2 = __builtin_bit_cast(f16x8, aw2);
        float P2[2], S2[2];
#pragma unroll
        for (int q = 0; q < 2; ++q) {
            f32x4 cin;
            cin[0] = cin[1] = cin[2] = cin[3] = bd2c[q];
            const f32x4 vd2 = __builtin_amdgcn_mfma_f32_16x16x32_f16(a2, bwd2[q], cin, 0, 0, 0);
            float sp = 1.f, sl = 0.f;
#pragma unroll
            for (int j = 0; j < 4; ++j) {
                const float delta = softplus_n(vd2[j]);
                const float ab    = fexp2(delta * nA2[q]);
                sl = ab * sl + delta * h1v[q][j];   // xin uses exact f32 h1
                sp *= ab;
            }
            P2[q] = sp; S2[q] = sl;
        }
#pragma unroll
        for (int q = 0; q < 2; ++q) {
            float Pm = __shfl(P2[q], lm16), Sm = __shfl(S2[q], lm16);
            if (grp >= 1) { S2[q] = P2[q] * Sm + S2[q]; P2[q] = P2[q] * Pm; }
            float Pm2 = __shfl(P2[q], lm32), Sm2 = __shfl(S2[q], lm32);
            if (grp >= 2) { S2[q] = P2[q] * Sm2 + S2[q]; P2[q] = P2[q] * Pm2; }
        }
        if (grp == 3) {
            cf2S[p][g][c0]      = make_float2(P2[0], S2[0]);
            cf2S[p][g][c0 + 16] = make_float2(P2[1], S2[1]);
        }

        // ---- COMB2 for tile it-1 (pipelined; cf2S[p^1] is barrier-separated) ----
        if (it > 0 && tid < 32) {
            float cy2 = s2v;
#pragma unroll
            for (int ch = 0; ch < NG; ++ch) {
                const float2 ax = cf2S[p ^ 1][ch][tid];
                cy2 = ax.x * cy2 + ax.y;
            }
            s2v = cy2;
        }

        // ---- commit prefetched x rows (wave-private region) ----
        if (it + 1 < NT) {
            const pk16 pk = __builtin_amdgcn_cvt_pkrtz(xnext.x, xnext.y);
            xs16[srow][sdc] = __builtin_bit_cast(unsigned int, pk);
        }
    }
    __syncthreads();

    // ---- final COMB2 (tile NT-1) + head ----
    if (tid < HH) {
        {
            float cy2 = s2v;
#pragma unroll
            for (int ch = 0; ch < NG; ++ch) {
                const float2 ax = cf2S[(NT - 1) & 1][ch][tid];
                cy2 = ax.x * cy2 + ax.y;
            }
            s2v = cy2;
        }
        float zg = bg[HH + tid];
#pragma unroll
        for (int k = 0; k < HH; ++k) zg += hlast[k] * Wg[HH * HH + k * HH + tid];
        const float gt2 = sigmoid_n(zg);
        const float h2  = hlast[tid] + s2v * gt2;

        float sum = h2;
#pragma unroll
        for (int m = 1; m < HH; m <<= 1) sum += __shfl_xor(sum, m);
        const float mu = sum * (1.0f / HH);
        const float d  = h2 - mu;
        float vs = d * d;
#pragma unroll
        for (int m = 1; m < HH; m <<= 1) vs += __shfl_xor(vs, m);
        const float rstd = rsqrtf(vs * (1.0f / HH) + 1e-5f);
        const float hn   = d * rstd * gmma[tid] + beta[tid];

        float z = b1[tid];
#pragma unroll
        for (int k = 0; k < HH; ++k) z += __shfl(hn, k) * W1[k * HH + tid];
        // gelu tanh-approx; tanh(t) = 1 - 2/(1+2^(2t*log2e))
        const float u  = 2.0f * L2E * 0.7978845608028654f * (z + 0.044715f * z * z * z);
        const float e  = fexp2(u);
        const float th = 1.f - 2.f * frcp(1.f + e);
        const float ge = 0.5f * z * (1.0f + th);
        float v = ge * W2[tid];
#pragma unroll
        for (int m = 1; m < HH; m <<= 1) v += __shfl_xor(v, m);
        if (tid == 0) out[b] = v + b2[0];
    }
}

extern "C" void kernel_launch(void* const* d_in, const int* in_sizes, int n_in,
                              void* d_out, int out_size, void* d_ws, size_t ws_size,
                              hipStream_t stream) {
    const float* x    = (const float*)d_in[0];
    const float* Wemb = (const float*)d_in[1];
    const float* bemb = (const float*)d_in[2];
    const float* Wd   = (const float*)d_in[3];
    const float* bd   = (const float*)d_in[4];
    const float* Alog = (const float*)d_in[5];
    const float* Wg   = (const float*)d_in[6];
    const float* bg   = (const float*)d_in[7];
    const float* gmma = (const float*)d_in[8];
    const float* beta = (const float*)d_in[9];
    const float* W1   = (const float*)d_in[10];
    const float* b1   = (const float*)d_in[11];
    const float* W2   = (const float*)d_in[12];
    const float* b2   = (const float*)d_in[13];
    float* out = (float*)d_out;

    forecast_fused<<<dim3(BB), dim3(NTHREADS), 0, stream>>>(
        x, Wemb, bemb, Wd, bd, Alog, Wg, bg, gmma, beta, W1, b1, W2, b2, out);
}